// Round 12
// baseline (43.137 us; speedup 1.0000x reference)
//
#include <hip/hip_runtime.h>
#include <hip/hip_bf16.h>
#include <cstdint>

// GraphLoss: result = sum(w*gold) + log(u1^T · M1·M2···M63 · exp(-wsink)),
// M_t[a][b] = exp(-w[64+(t-1)*4096 + a*64 + b]).
//
// R12: DEPTH REDUCTION via associativity. 16 stage-1 wgs each compute
// T_g = (M_{L1}···M_{L2})^T = M_{L2}^T···M_{L1}^T (<=3 chained 64x64 f32
// matmuls, operands LDS-resident, staged by global_load_lds + in-place exp).
// One stage-2 wg chains x <- T_g·x (g=0..15) with per-step renorm by x[0]
// (LS accumulates log scale), fed by a 3-slot LDS ring filled by two
// alternating DMA waves (all waits vmcnt(0): per-wave counters, no counted
// vmcnt, no VGPR load targets -> R3-R10 hazard classes impossible).
// 128 gold wgs reduce sum(w*gold). Flags: R9-proven MAGIC protocol in d_ws
// (poison 0xAA != MAGIC; producers release MAGIC, consumers reset to 0).
// Everything f32; single kernel launch.
//
// T image layout (both U-lds in stage-1 and d_ws): word (r*64 + c) XOR
// ((r&7)<<2)  [16B-granular row swizzle -> conflict-free row reads].

typedef float v2f   __attribute__((ext_vector_type(2)));
typedef float f32x4 __attribute__((ext_vector_type(4)));
typedef __attribute__((address_space(3))) unsigned int as3_u32;
typedef __attribute__((address_space(1))) const unsigned int as1_u32;

#define NGRP 16
#define NGOLD 128
#define MAGIC 0x5EC0FFEEu
#define SINK_BASE (64 + 63 * 4096)   // 258112
#define TBW 1024                     // word offset of T region in ws
// ws words: U[0..16) stage1 flags | U[16..144) gold flags | F[256..384) gold
// partials | F[1024 .. 1024+16*4096) T-matrices (16KB each)

#define BAR_VL() do { asm volatile("s_waitcnt vmcnt(0) lgkmcnt(0)" ::: "memory"); \
                      __builtin_amdgcn_s_barrier(); } while (0)
#define BAR_L()  do { asm volatile("s_waitcnt lgkmcnt(0)" ::: "memory");          \
                      __builtin_amdgcn_s_barrier(); } while (0)

__global__ __launch_bounds__(256, 1)
void fused_kernel(const int* __restrict__ g, const float* __restrict__ w,
                  float* __restrict__ wsF, float* __restrict__ out, int E) {
    __shared__ __align__(16) float LDSF[16448];
    unsigned int* wsU  = (unsigned int*)wsF;
    unsigned int* ldsu = (unsigned int*)LDSF;
    const int bid = blockIdx.x, tid = threadIdx.x;
    const int wv = tid >> 6, l = tid & 63;

    if (bid >= NGRP + 1) {
        // ---------------- gold reduction (R9-proven) ----------------
        const int gw = bid - (NGRP + 1);
        const bool is64 = (g[1] == 0);
        float s = 0.f;
        for (int e = gw * 256 + tid; e < E; e += NGOLD * 256) {
            const int idx = 3 * e + 2;
            const int gvv = is64 ? g[2 * idx] : g[idx];
            s += w[e] * (float)gvv;
        }
        #pragma unroll
        for (int d = 1; d < 64; d <<= 1) s += __shfl_xor(s, d, 64);
        if (l == 0) LDSF[wv] = s;
        __syncthreads();
        if (tid == 0) {
            const float tt = LDSF[0] + LDSF[1] + LDSF[2] + LDSF[3];
            __hip_atomic_store(&wsF[256 + gw], tt, __ATOMIC_RELAXED, __HIP_MEMORY_SCOPE_AGENT);
            __hip_atomic_store(&wsU[16 + gw], MAGIC, __ATOMIC_RELEASE, __HIP_MEMORY_SCOPE_AGENT);
        }
        return;
    }

    if (bid < NGRP) {
        // ---------------- stage 1: T_g = M_L2^T ··· M_L1^T ----------------
        const int gg = bid;
        const int L1 = 4 * gg + 1;
        const int L2 = (gg == 15) ? 63 : (4 * gg + 4);
        const int nmm = L2 - L1;            // 3 (or 2 for g=15)
        const int bb = 16 * wv + (l & 15);  // output column
        const int rg = l >> 4;              // row group

        // DMA one level's raw w (4096 f32) linearly into LDS words [LB..LB+4096)
#define DMA4K(LB, T) do {                                                      \
        const unsigned int* _s = (const unsigned int*)(w + 64 + ((T) - 1) * 4096) \
                                 + wv * 1024 + l * 4;                          \
        _Pragma("unroll")                                                      \
        for (int _j = 0; _j < 4; ++_j)                                         \
            __builtin_amdgcn_global_load_lds((as1_u32*)(_s + _j * 256),        \
                (as3_u32*)(ldsu + (LB) + wv * 1024 + _j * 256), 16, 0, 0);     \
    } while (0)

        // pre: U0 = exp-transposed M_L2; B0 <- M_{L2-1}; B1 <- M_{L2-2}
        DMA4K(4096, L2);                     // raw image into U1 region (tmp)
        BAR_VL();
        DMA4K(8192, L2 - 1);                 // B0
        {   // transpose+exp: U0[r][k] = exp(-img[k*64+r]) (img = [a=k][b=r])
            const int k = tid >> 2, rb = (tid & 3) * 16;
            #pragma unroll
            for (int j = 0; j < 16; ++j) {
                const float v = __expf(-LDSF[4096 + 16 * tid + j]);
                const int r = rb + j;
                LDSF[(r * 64 + k) ^ ((r & 7) << 2)] = v;
            }
        }
        BAR_VL();                             // drains B0 DMA + transpose writes
        #pragma unroll
        for (int j = 0; j < 16; ++j)          // exp-pass B0 in place
            LDSF[8192 + 16 * tid + j] = __expf(-LDSF[8192 + 16 * tid + j]);
        DMA4K(12288, L2 - 2);                 // B1 (in flight across next mm)
        BAR_L();

        #pragma unroll 1
        for (int mi = 0; mi < nmm; ++mi) {
            const int AU = (mi & 1) ? 4096 : 0;
            const int BU = (mi & 1) ? 12288 : 8192;
            const int WU = (mi & 1) ? 0 : 4096;
            const bool last = (mi == nmm - 1);
            // B column bb (64 f32) -> regs (linear image word bb*64+k)
            f32x4 bcq[16];
            #pragma unroll
            for (int i = 0; i < 16; ++i)
                bcq[i] = *(const f32x4*)&LDSF[BU + bb * 64 + 4 * i];
            // 16 rows per thread, staggered so the 4 rg's hit distinct swz slots
            #pragma unroll 1
            for (int i = 0; i < 16; ++i) {
                const int r = rg * 16 + ((i + 2 * rg) & 15);
                const int sw = (r & 7) << 2;
                v2f a0 = {0.f,0.f}, a1 = {0.f,0.f}, a2 = {0.f,0.f}, a3 = {0.f,0.f};
                #pragma unroll
                for (int j = 0; j < 16; ++j) {
                    const f32x4 uq = *(const f32x4*)&LDSF[AU + ((r * 64 + 4 * j) ^ sw)];
                    v2f u01, u23, b01, b23;
                    u01[0] = uq[0]; u01[1] = uq[1]; u23[0] = uq[2]; u23[1] = uq[3];
                    b01[0] = bcq[j][0]; b01[1] = bcq[j][1];
                    b23[0] = bcq[j][2]; b23[1] = bcq[j][3];
                    if (j & 1) { a2 = __builtin_elementwise_fma(u01, b01, a2);
                                 a3 = __builtin_elementwise_fma(u23, b23, a3); }
                    else       { a0 = __builtin_elementwise_fma(u01, b01, a0);
                                 a1 = __builtin_elementwise_fma(u23, b23, a1); }
                }
                const v2f s2 = (a0 + a1) + (a2 + a3);
                const float y = s2[0] + s2[1];
                if (last) wsF[TBW + gg * 4096 + ((r * 64 + bb) ^ sw)] = y;
                else      LDSF[WU + ((r * 64 + bb) ^ sw)] = y;
            }
            if (!last) {
                BAR_VL();                     // drains U' writes + pending DMA
                const int NB = (mi & 1) ? 8192 : 12288;   // buffer for mm(mi+1)
                #pragma unroll
                for (int j = 0; j < 16; ++j)
                    LDSF[NB + 16 * tid + j] = __expf(-LDSF[NB + 16 * tid + j]);
                if (L2 - 3 - mi >= L1) DMA4K(BU, L2 - 3 - mi);
                BAR_L();
            }
        }
        asm volatile("s_waitcnt vmcnt(0)" ::: "memory");
        __syncthreads();
        if (tid == 0)
            __hip_atomic_store(&wsU[bid], MAGIC, __ATOMIC_RELEASE, __HIP_MEMORY_SCOPE_AGENT);
        return;
    }

    // ---------------- stage 2: x <- T_g · x, g = 0..15 ----------------
    // wave 0 = consumer (lane c); waves 1,2 = alternating DMA producers;
    // wave 3 = barrier companion. 3-slot ring, windows -2..15.
    const int c = l;
    float LS = 0.f, xr = 0.f, wsink = 0.f;
    if (wv == 0) {
        const float z1 = -w[c];
        LS = __int_as_float(__builtin_amdgcn_readfirstlane(__float_as_int(z1)));
        xr = __expf(z1 - LS);                 // x[0] = 1
        LDSF[12288 + c] = xr;
        wsink = w[SINK_BASE + c];
    }
    #pragma unroll 1
    for (int ww = -2; ww <= 15; ++ww) {
        if (wv == 1 || wv == 2) {
            const int par = wv - 1;           // P0: even g, P1: odd g
            if (ww + 1 >= 0 && ww + 1 <= 15 && ((ww + 1) & 1) == par)
                asm volatile("s_waitcnt vmcnt(0)" ::: "memory");   // drain my DMA(ww+1)
            const int gi = ww + 2;
            if (gi <= 15 && (gi & 1) == par) {
                while (__hip_atomic_load(&wsU[gi], __ATOMIC_ACQUIRE,
                                         __HIP_MEMORY_SCOPE_AGENT) != MAGIC)
                    __builtin_amdgcn_s_sleep(1);
                if (l == 0)
                    __hip_atomic_store(&wsU[gi], 0u, __ATOMIC_RELAXED,
                                       __HIP_MEMORY_SCOPE_AGENT);
                const unsigned int* src = (const unsigned int*)wsF + TBW + gi * 4096 + l * 4;
                const int sb = (gi % 3) * 4096;
                #pragma unroll
                for (int j = 0; j < 16; ++j)
                    __builtin_amdgcn_global_load_lds((as1_u32*)(src + j * 256),
                        (as3_u32*)(ldsu + sb + j * 256), 16, 0, 0);
            }
        } else if (wv == 0 && ww >= 0) {
            const int sb = (ww % 3) * 4096;
            const int sw = (c & 7) << 2;
            v2f a0 = {0.f,0.f}, a1 = {0.f,0.f}, a2 = {0.f,0.f}, a3 = {0.f,0.f};
            #pragma unroll
            for (int j = 0; j < 16; ++j) {
                const f32x4 tq = *(const f32x4*)&LDSF[sb + ((c * 64 + 4 * j) ^ sw)];
                const f32x4 xq = *(const f32x4*)&LDSF[12288 + 4 * j];
                v2f t01, t23, x01, x23;
                t01[0] = tq[0]; t01[1] = tq[1]; t23[0] = tq[2]; t23[1] = tq[3];
                x01[0] = xq[0]; x01[1] = xq[1]; x23[0] = xq[2]; x23[1] = xq[3];
                if (j & 1) { a2 = __builtin_elementwise_fma(t01, x01, a2);
                             a3 = __builtin_elementwise_fma(t23, x23, a3); }
                else       { a0 = __builtin_elementwise_fma(t01, x01, a0);
                             a1 = __builtin_elementwise_fma(t23, x23, a1); }
            }
            const v2f s2 = (a0 + a1) + (a2 + a3);
            const float ov = s2[0] + s2[1];
            const float rho = __int_as_float(__builtin_amdgcn_readfirstlane(__float_as_int(ov)));
            float rc;
            asm("v_rcp_f32 %0, %1" : "=v"(rc) : "v"(rho));
            LS += __logf(rho);
            xr = ov * rc;
            LDSF[12288 + c] = xr;
        }
        asm volatile("s_waitcnt lgkmcnt(0)" ::: "memory");
        __builtin_amdgcn_s_barrier();
    }
    if (wv == 0) {
        // sink fold: m[c] = z64[c] - wsink[c]
        float m = LS + __logf(xr) - wsink;
        float s = 1.0f;
        #pragma unroll
        for (int d = 1; d < 64; d <<= 1) {
            const float om = __shfl_xor(m, d, 64);
            const float os = __shfl_xor(s, d, 64);
            const float nm = fmaxf(m, om);
            s = __expf(m - nm) * s + __expf(om - nm) * os;
            m = nm;
        }
        const float vsink = m + __logf(s);
        // gold gather (2 partials per lane)
        float gv = 0.f;
        #pragma unroll 1
        for (int i = 0; i < 2; ++i) {
            const int gw = c + 64 * i;
            while (__hip_atomic_load(&wsU[16 + gw], __ATOMIC_ACQUIRE,
                                     __HIP_MEMORY_SCOPE_AGENT) != MAGIC)
                __builtin_amdgcn_s_sleep(2);
            gv += wsF[256 + gw];
            __hip_atomic_store(&wsU[16 + gw], 0u, __ATOMIC_RELAXED,
                               __HIP_MEMORY_SCOPE_AGENT);
        }
        #pragma unroll
        for (int d = 1; d < 64; d <<= 1) gv += __shfl_xor(gv, d, 64);
        if (c == 0) out[0] = gv + vsink;
    }
}

extern "C" void kernel_launch(void* const* d_in, const int* in_sizes, int n_in,
                              void* d_out, int out_size, void* d_ws, size_t ws_size,
                              hipStream_t stream) {
    const int*   g = (const int*)d_in[0];
    const float* w = (const float*)d_in[1];
    float* out     = (float*)d_out;
    float* ws      = (float*)d_ws;
    const int E = in_sizes[0] / 3;   // 258176

    fused_kernel<<<NGRP + 1 + NGOLD, 256, 0, stream>>>(g, w, ws, out, E);
}

// Round 13
// 34.654 us; speedup vs baseline: 1.2448x; 1.2448x over previous
//
#include <hip/hip_runtime.h>
#include <hip/hip_bf16.h>
#include <cstdint>

// GraphLoss single-kernel fused pipeline.
// result = sum(w*gold) + logsumexp over all source->sink paths of (-path weight).
//
// Roles by blockIdx (128 wgs x 256 thr, all co-resident on 256 CUs):
//   wg 0                  : chain (R8-verbatim 4-wave body + R11 multiplicative renorm)
//   wgs 8,16,...,120 (15) : converters -> wpk = packed bf16 exp(-w) (R8 prep layout).
//                           Same XCD as wg 0 under round-robin dispatch => wpk stays
//                           in the chain's local L2 (heuristic: affects speed only).
//   other 112 wgs         : gold partials sum(w*gold), fixed-order gather (deterministic).
// Flags: R9-proven MAGIC protocol in d_ws (0xAA poison != MAGIC; producer release,
// consumer resets to 0; launches serialize on stream => replay-safe).
//
// Chain hazard rules (R3-R7 lessons, all kept): counted vmcnt only on the 8
// inline-asm load targets; no dummy loads; peeled tail 6/4/2/0 leaves ZERO in
// flight; "+v" pin after each wait; sched_barrier(0) after waits; all
// compiler-visible VMEM drained (vmcnt(0)) before the first counted ISSUE;
// in-loop barriers are raw s_barrier + lgkmcnt(0) (never __syncthreads).
//
// Edge layout: e in [0,64): source->layer1 ; e = 64 + L*4096 + a*64 + b ;
// e = 258112 + j: layer64 node j -> sink.

typedef float v2f   __attribute__((ext_vector_type(2)));
typedef float f32x4 __attribute__((ext_vector_type(4)));
typedef unsigned int u32x4 __attribute__((ext_vector_type(4)));

#define NLV 63
#define NPACK (63 * 2048)            // packed u32 words (8KB/level)
#define SINK_BASE (64 + 63 * 4096)   // 258112
#define MAGIC 0x5EC0FFEEu
#define NCONV 15
#define NGOLD 112
#define WPKW 1024                    // word offset of wpk region in ws
// ws words: U[0..15) conv flags | U[16..128) gold flags | F[256..368) gold
// partials | U[1024..1024+129024) wpk

__global__ __launch_bounds__(256, 1)
void fused_kernel(const int* __restrict__ g, const float* __restrict__ w,
                  float* __restrict__ wsF, float* __restrict__ out, int E) {
    __shared__ __align__(16) float ubuf[2][64];
    __shared__ float P[2];
    __shared__ float slds[64];
    __shared__ float gred[4];

    unsigned int* wsU = (unsigned int*)wsF;
    unsigned int* wpk = (unsigned int*)wsF + WPKW;
    const int bid = blockIdx.x, tid = threadIdx.x;
    const int wv = tid >> 6, l = tid & 63;

    if (bid != 0) {
        if ((bid & 7) == 0 && bid <= 120) {
            // ---------- converter (R8 prep formula verbatim, proven) ----------
            const int cid = (bid >> 3) - 1;
            for (int f = cid * 256 + tid; f < NPACK; f += NCONV * 256) {
                const int L = f >> 11;
                const int r = f & 2047;
                const int h = (r >> 10) & 1;
                const int t = (r >> 2) & 255;
                const int q = r & 3;
                const int wvp = t >> 6, ls = t & 63;
                const int kcp = ls >> 4, bp = 16 * wvp + (ls & 15);
                const int k = 16 * kcp + 2 * (4 * h + q);
                const int e0 = 64 + L * 4096 + k * 64 + bp;
                const float x0 = __expf(-w[e0]);
                const float x1 = __expf(-w[e0 + 64]);
                uint32_t u0 = __float_as_uint(x0); u0 = (u0 + 0x7fffu + ((u0 >> 16) & 1u)) >> 16;
                uint32_t u1 = __float_as_uint(x1); u1 = (u1 + 0x7fffu + ((u1 >> 16) & 1u)) >> 16;
                wpk[f] = u0 | (u1 << 16);
            }
            __syncthreads();
            if (tid == 0)
                __hip_atomic_store(&wsU[cid], MAGIC, __ATOMIC_RELEASE,
                                   __HIP_MEMORY_SCOPE_AGENT);
        } else {
            // ---------- gold partial (R9 verbatim, proven) ----------
            const int gid = bid - 1 - (bid >> 3);      // dense 0..111
            const bool is64 = (g[1] == 0);
            float s = 0.f;
            for (int e = gid * 256 + tid; e < E; e += NGOLD * 256) {
                const int idx = 3 * e + 2;
                const int gv = is64 ? g[2 * idx] : g[idx];
                s += w[e] * (float)gv;
            }
            #pragma unroll
            for (int d = 1; d < 64; d <<= 1) s += __shfl_xor(s, d, 64);
            if (l == 0) gred[wv] = s;
            __syncthreads();
            if (tid == 0) {
                const float tt = gred[0] + gred[1] + gred[2] + gred[3];
                __hip_atomic_store(&wsF[256 + gid], tt, __ATOMIC_RELAXED,
                                   __HIP_MEMORY_SCOPE_AGENT);
                __hip_atomic_store(&wsU[16 + gid], MAGIC, __ATOMIC_RELEASE,
                                   __HIP_MEMORY_SCOPE_AGENT);
            }
        }
        return;
    }

    // ==================== chain wg (R8 core + R11 renorm) ====================
    const int kc = l >> 4;
    const int bb = 16 * wv + (l & 15);

    // compiler-visible loads, pinned complete before any counted-vmcnt asm
    const float z10 = -w[0];
    float LS = z10;
    float uf = __expf(-w[bb] - z10);       // u_1[bb], u_1[0] = 1
    float wsink = w[SINK_BASE + bb];
    asm volatile("" : "+v"(LS), "+v"(uf), "+v"(wsink));

    // wait for all 15 converter flags (wave 0 spins, others hold at barrier)
    if (wv == 0 && l < NCONV) {
        while (__hip_atomic_load(&wsU[l], __ATOMIC_ACQUIRE,
                                 __HIP_MEMORY_SCOPE_AGENT) != MAGIC)
            __builtin_amdgcn_s_sleep(1);
    }
    __syncthreads();                        // full sync: flags seen by all
    if (tid < NCONV) wsU[tid] = 0u;         // reset for next launch
    asm volatile("s_waitcnt vmcnt(0)" ::: "memory");  // drain resets+spins

    if (l < 16) ubuf[0][bb] = uf;
    if (tid == 0) P[0] = 1.0f;

    const uint32_t voff  = (uint32_t)tid * 16u;
    const uint32_t voff2 = voff + 4096u;
    uintptr_t bcur = (uintptr_t)wpk;
    u32x4 q0a, q0b, q1a, q1b, q2a, q2b, q3a, q3b;

#define LD1(DST, VO)                                                           \
    asm volatile("global_load_dwordx4 %0, %1, %2"                              \
                 : "=v"(DST) : "v"(VO), "s"(bcur))

#define ISSUE(QA, QB) do { LD1(QA, voff); LD1(QB, voff2); bcur += 8192u; } while (0)

#define BAR() do {                                                             \
    asm volatile("s_waitcnt lgkmcnt(0)" ::: "memory");                         \
    __builtin_amdgcn_s_barrier();                                              \
} while (0)

// body t: CB = t&1. Reads ubuf[CB]/P[CB], writes ubuf[CB^1]/P[CB^1].
// Multiplicative renorm (R11 algebra, proven): uf = p * rcp(rho); LS += log(rho).
#define BODY(QA, QB, CB, WSTR, DOISS) {                                        \
    asm volatile("s_waitcnt vmcnt(" WSTR ")" ::: "memory");                    \
    __builtin_amdgcn_sched_barrier(0);                                         \
    asm volatile("" : "+v"(QA), "+v"(QB));                                     \
    const float rho = P[CB];                                                   \
    float rc;                                                                  \
    asm("v_rcp_f32 %0, %1" : "=v"(rc) : "v"(rho));                             \
    const f32x4* uq = (const f32x4*)ubuf[CB];                                  \
    v2f acc = {0.f, 0.f};                                                      \
    _Pragma("unroll")                                                          \
    for (int m = 0; m < 4; ++m) {                                              \
        const f32x4 uu = uq[4 * kc + m];                                       \
        _Pragma("unroll")                                                      \
        for (int pp = 0; pp < 2; ++pp) {                                       \
            const int j2 = 2 * m + pp;                                         \
            const unsigned int wd = (j2 < 4) ? QA[j2] : QB[j2 - 4];            \
            v2f wp, up;                                                        \
            wp[0] = __uint_as_float(wd << 16);                                 \
            wp[1] = __uint_as_float(wd & 0xffff0000u);                         \
            up[0] = uu[2 * pp]; up[1] = uu[2 * pp + 1];                        \
            acc = __builtin_elementwise_fma(wp, up, acc);                      \
        }                                                                      \
    }                                                                          \
    float p = acc[0] + acc[1];                                                 \
    p += __shfl_xor(p, 16, 64);                                                \
    p += __shfl_xor(p, 32, 64);           /* p = y[bb], all lanes */           \
    uf = p * rc;                                                               \
    LS += __logf(rho);                    /* off critical path */              \
    if (l < 16) ubuf[(CB) ^ 1][bb] = uf;                                       \
    if (tid == 0) P[(CB) ^ 1] = uf;                                            \
    if (DOISS) ISSUE(QA, QB);                                                  \
    BAR();                                                                     \
}

    ISSUE(q0a, q0b);   // level 0
    ISSUE(q1a, q1b);   // level 1
    ISSUE(q2a, q2b);   // level 2
    ISSUE(q3a, q3b);   // level 3
    BAR();             // ubuf[0]/P[0] visible

    // bodies 0..55
    #pragma unroll 1
    for (int it = 0; it < 14; ++it) {
        BODY(q0a, q0b, 0, "6", 1)
        BODY(q1a, q1b, 1, "6", 1)
        BODY(q2a, q2b, 0, "6", 1)
        BODY(q3a, q3b, 1, "6", 1)
    }
    // peeled tail: bodies 56..62; last issue at body 58 (level 62);
    // exact waits leave ZERO loads in flight after body 62.
    BODY(q0a, q0b, 0, "6", 1)   // 56 -> issues L60
    BODY(q1a, q1b, 1, "6", 1)   // 57 -> issues L61
    BODY(q2a, q2b, 0, "6", 1)   // 58 -> issues L62
    BODY(q3a, q3b, 1, "6", 0)   // 59
    BODY(q0a, q0b, 0, "4", 0)   // 60
    BODY(q1a, q1b, 1, "2", 0)   // 61
    BODY(q2a, q2b, 0, "0", 0)   // 62

    // sink fold staging: m[bb] = z64[bb] - wsink = LS + log(uf) - wsink
    const float m0 = LS + __logf(uf) - wsink;
    if (l < 16) slds[bb] = m0;
    BAR();

    if (wv == 0) {
        float m = slds[l];
        float s = 1.0f;
        #pragma unroll
        for (int d = 1; d < 64; d <<= 1) {
            const float om = __shfl_xor(m, d, 64);
            const float os = __shfl_xor(s, d, 64);
            const float nm = fmaxf(m, om);
            s = __expf(m - nm) * s + __expf(om - nm) * os;
            m = nm;
        }
        const float vsink = m + __logf(s);

        // gold gather, fixed order (deterministic)
        float gv = 0.f;
        {
            while (__hip_atomic_load(&wsU[16 + l], __ATOMIC_ACQUIRE,
                                     __HIP_MEMORY_SCOPE_AGENT) != MAGIC)
                __builtin_amdgcn_s_sleep(2);
            gv = wsF[256 + l];
            __hip_atomic_store(&wsU[16 + l], 0u, __ATOMIC_RELAXED,
                               __HIP_MEMORY_SCOPE_AGENT);
        }
        if (l < NGOLD - 64) {   // 48 more
            while (__hip_atomic_load(&wsU[16 + 64 + l], __ATOMIC_ACQUIRE,
                                     __HIP_MEMORY_SCOPE_AGENT) != MAGIC)
                __builtin_amdgcn_s_sleep(2);
            gv += wsF[256 + 64 + l];
            __hip_atomic_store(&wsU[16 + 64 + l], 0u, __ATOMIC_RELAXED,
                               __HIP_MEMORY_SCOPE_AGENT);
        }
        #pragma unroll
        for (int d = 1; d < 64; d <<= 1) gv += __shfl_xor(gv, d, 64);
        if (l == 0) out[0] = gv + vsink;
    }
}

extern "C" void kernel_launch(void* const* d_in, const int* in_sizes, int n_in,
                              void* d_out, int out_size, void* d_ws, size_t ws_size,
                              hipStream_t stream) {
    const int*   g = (const int*)d_in[0];
    const float* w = (const float*)d_in[1];
    float* out     = (float*)d_out;
    float* ws      = (float*)d_ws;
    const int E = in_sizes[0] / 3;   // 258176

    fused_kernel<<<128, 256, 0, stream>>>(g, w, ws, out, E);
}

// Round 14
// 28.346 us; speedup vs baseline: 1.5218x; 1.2225x over previous
//
#include <hip/hip_runtime.h>
#include <hip/hip_bf16.h>
#include <cstdint>

// GraphLoss: layered lattice DAG (64 layers x 64 nodes, dense bipartite).
// result = sum(w*gold) + logsumexp over all source->sink paths of (-path weight).
//
// R14 = R8 (best, 30.7us) with the prefetch pipeline deepened 4 -> 10 levels.
// Rationale: seq's ~800cy/level = ~400 compute + ~latency/depth stall; wpk is
// dirty in other XCDs' L2s (~1400cy). depth 10 => stall ~140cy/body.
// Chain body numerics = R13's multiplicative renorm (proven absmax 0.0):
//   u_next = p * rcp(rho), rho = prev u[0]; LS += log(rho) off-path.
// prep = R8 verbatim (proven). All hazard rules from R3-R7 kept:
//   counted vmcnt only on inline-asm load targets; no dummy loads; peeled
//   tail with exact waits 18/16/.../0 -> ZERO loads in flight at exit;
//   "+v" pin after each wait; sched_barrier(0) fences; raw s_barrier +
//   lgkmcnt(0) in-loop (never __syncthreads).
//
// Edge layout: e in [0,64): source->layer1 ; e = 64 + L*4096 + a*64 + b ;
// e = 258112 + j: layer64 node j -> sink.

typedef float v2f   __attribute__((ext_vector_type(2)));
typedef float f32x4 __attribute__((ext_vector_type(4)));
typedef unsigned int u32x4 __attribute__((ext_vector_type(4)));

#define NLV 63
#define NPACK (63 * 2048)            // packed u32 words (8KB/level)
#define SINK_BASE (64 + 63 * 4096)   // 258112
#define NPB 256

// ---------------------------------------------------------------------------
// prep (R8 verbatim, proven absmax 0.0): word f = L*2048 + h*1024 + t*4 + q,
// t in [0,256): kc=(t&63)>>4, bb=16*(t>>6)+(t&15), pair k = 16kc+2*(4h+q):
// packs bf16(exp(-w[e0])) | bf16(exp(-w[e0+64]))<<16, e0 = 64+L*4096+k*64+bb.
// Seq thread t reads its 2 quads at bytes L*8192 + t*16 and +4096. Coalesced.
// Plus 256 block partials of sum(w*gold).
__global__ __launch_bounds__(512)
void prep_kernel(const int* __restrict__ g, const float* __restrict__ w,
                 unsigned int* __restrict__ wpk, float* __restrict__ partial, int E) {
    const int f = blockIdx.x * blockDim.x + threadIdx.x;
    if (f < NPACK) {
        const int L = f >> 11;
        const int r = f & 2047;
        const int h = (r >> 10) & 1;
        const int t = (r >> 2) & 255;
        const int q = r & 3;
        const int wvp = t >> 6, ls = t & 63;
        const int kcp = ls >> 4, bp = 16 * wvp + (ls & 15);
        const int k = 16 * kcp + 2 * (4 * h + q);
        const int e0 = 64 + L * 4096 + k * 64 + bp;
        const float x0 = __expf(-w[e0]);
        const float x1 = __expf(-w[e0 + 64]);
        uint32_t u0 = __float_as_uint(x0); u0 = (u0 + 0x7fffu + ((u0 >> 16) & 1u)) >> 16;
        uint32_t u1 = __float_as_uint(x1); u1 = (u1 + 0x7fffu + ((u1 >> 16) & 1u)) >> 16;
        wpk[f] = u0 | (u1 << 16);
    }
    const bool is64 = (g[1] == 0);
    float s = 0.f;
    const int stride = gridDim.x * blockDim.x;
    for (int e = f; e < E; e += stride) {
        const int idx = 3 * e + 2;
        const int gv = is64 ? g[2 * idx] : g[idx];
        s += w[e] * (float)gv;
    }
    #pragma unroll
    for (int dd = 1; dd < 64; dd <<= 1) s += __shfl_xor(s, dd, 64);
    __shared__ float lsm[8];
    const int wv = threadIdx.x >> 6, ln = threadIdx.x & 63;
    if (ln == 0) lsm[wv] = s;
    __syncthreads();
    if (threadIdx.x == 0) {
        float tt = 0.f;
        #pragma unroll
        for (int i = 0; i < 8; ++i) tt += lsm[i];
        partial[blockIdx.x] = tt;
    }
}

// ---------------------------------------------------------------------------
// seq: 256 threads / 4 waves. Wave wv owns nodes 16wv..16wv+15; lane computes
// the 16-term k-chunk (kc) partial for b=16wv+(l&15); fold shfl_xor(16,32).
__global__ __launch_bounds__(256, 1)
void seq_kernel(const float* __restrict__ w, const unsigned int* __restrict__ wpk,
                const float* __restrict__ partial, float* __restrict__ out) {
    __shared__ __align__(16) float ubuf[2][64];
    __shared__ float P[2];
    __shared__ float slds[64];

    const int tid = threadIdx.x;
    const int wv = tid >> 6, l = tid & 63;
    const int kc = l >> 4;
    const int bb = 16 * wv + (l & 15);

    // compiler-visible loads, pinned complete before the counted-asm stream
    const float z10 = -w[0];
    float LS = z10;
    float uf = __expf(-w[bb] - z10);       // u_1[bb]; u_1[0] = 1
    float wsink = w[SINK_BASE + bb];
    float gs = 0.f;
    #pragma unroll
    for (int i = 0; i < 4; ++i) gs += partial[l + (i << 6)];
    asm volatile("" : "+v"(LS), "+v"(uf), "+v"(wsink), "+v"(gs));

    if (l < 16) ubuf[0][bb] = uf;
    if (tid == 0) P[0] = 1.0f;

    const uint32_t voff  = (uint32_t)tid * 16u;
    const uint32_t voff2 = voff + 4096u;
    uintptr_t bcur = (uintptr_t)wpk;

    u32x4 q0a, q0b, q1a, q1b, q2a, q2b, q3a, q3b, q4a, q4b;
    u32x4 q5a, q5b, q6a, q6b, q7a, q7b, q8a, q8b, q9a, q9b;

#define LD1(DST, VO)                                                           \
    asm volatile("global_load_dwordx4 %0, %1, %2"                              \
                 : "=v"(DST) : "v"(VO), "s"(bcur))

#define ISSUE(QA, QB) do { LD1(QA, voff); LD1(QB, voff2); bcur += 8192u; } while (0)

#define BAR() do {                                                             \
    asm volatile("s_waitcnt lgkmcnt(0)" ::: "memory");                         \
    __builtin_amdgcn_s_barrier();                                              \
} while (0)

// body t: CB = t&1. Reads ubuf[CB]/P[CB], writes ubuf[CB^1]/P[CB^1].
#define BODY(QA, QB, CB, WSTR, DOISS) {                                        \
    asm volatile("s_waitcnt vmcnt(" WSTR ")" ::: "memory");                    \
    __builtin_amdgcn_sched_barrier(0);                                         \
    asm volatile("" : "+v"(QA), "+v"(QB));                                     \
    const float rho = P[CB];                                                   \
    float rc;                                                                  \
    asm("v_rcp_f32 %0, %1" : "=v"(rc) : "v"(rho));                             \
    const f32x4* uq = (const f32x4*)ubuf[CB];                                  \
    v2f acc = {0.f, 0.f};                                                      \
    _Pragma("unroll")                                                          \
    for (int m = 0; m < 4; ++m) {                                              \
        const f32x4 uu = uq[4 * kc + m];                                       \
        _Pragma("unroll")                                                      \
        for (int pp = 0; pp < 2; ++pp) {                                       \
            const int j2 = 2 * m + pp;                                         \
            const unsigned int wd = (j2 < 4) ? QA[j2] : QB[j2 - 4];            \
            v2f wp, up;                                                        \
            wp[0] = __uint_as_float(wd << 16);                                 \
            wp[1] = __uint_as_float(wd & 0xffff0000u);                         \
            up[0] = uu[2 * pp]; up[1] = uu[2 * pp + 1];                        \
            acc = __builtin_elementwise_fma(wp, up, acc);                      \
        }                                                                      \
    }                                                                          \
    float p = acc[0] + acc[1];                                                 \
    p += __shfl_xor(p, 16, 64);                                                \
    p += __shfl_xor(p, 32, 64);           /* p = y[bb] in all lanes */         \
    uf = p * rc;                                                               \
    LS += __logf(rho);                    /* off critical path */              \
    if (l < 16) ubuf[(CB) ^ 1][bb] = uf;                                       \
    if (tid == 0) P[(CB) ^ 1] = uf;                                            \
    if (DOISS) ISSUE(QA, QB);                                                  \
    BAR();                                                                     \
}

    // prologue: levels 0..9 in flight (20 loads)
    ISSUE(q0a, q0b); ISSUE(q1a, q1b); ISSUE(q2a, q2b); ISSUE(q3a, q3b);
    ISSUE(q4a, q4b); ISSUE(q5a, q5b); ISSUE(q6a, q6b); ISSUE(q7a, q7b);
    ISSUE(q8a, q8b); ISSUE(q9a, q9b);
    BAR();             // ubuf[0]/P[0] visible

    // bodies 0..49 (5 x 10-body rotation); body t consumes level t, issues t+10
    #pragma unroll 1
    for (int it = 0; it < 5; ++it) {
        BODY(q0a, q0b, 0, "18", 1)
        BODY(q1a, q1b, 1, "18", 1)
        BODY(q2a, q2b, 0, "18", 1)
        BODY(q3a, q3b, 1, "18", 1)
        BODY(q4a, q4b, 0, "18", 1)
        BODY(q5a, q5b, 1, "18", 1)
        BODY(q6a, q6b, 0, "18", 1)
        BODY(q7a, q7b, 1, "18", 1)
        BODY(q8a, q8b, 0, "18", 1)
        BODY(q9a, q9b, 1, "18", 1)
    }
    // peeled tail: bodies 50..62; last issue at body 52 (level 62);
    // exact waits leave ZERO loads in flight after body 62.
    BODY(q0a, q0b, 0, "18", 1)   // 50 -> L60
    BODY(q1a, q1b, 1, "18", 1)   // 51 -> L61
    BODY(q2a, q2b, 0, "18", 1)   // 52 -> L62
    BODY(q3a, q3b, 1, "18", 0)   // 53
    BODY(q4a, q4b, 0, "16", 0)   // 54
    BODY(q5a, q5b, 1, "14", 0)   // 55
    BODY(q6a, q6b, 0, "12", 0)   // 56
    BODY(q7a, q7b, 1, "10", 0)   // 57
    BODY(q8a, q8b, 0, "8",  0)   // 58
    BODY(q9a, q9b, 1, "6",  0)   // 59
    BODY(q0a, q0b, 0, "4",  0)   // 60
    BODY(q1a, q1b, 1, "2",  0)   // 61
    BODY(q2a, q2b, 0, "0",  0)   // 62

    // sink fold staging: m[bb] = LS + log(uf) - wsink
    const float m0 = LS + __logf(uf) - wsink;
    if (l < 16) slds[bb] = m0;
    BAR();

    if (wv == 0) {
        float m = slds[l];
        float s = 1.0f;
        #pragma unroll
        for (int d = 1; d < 64; d <<= 1) {
            const float om = __shfl_xor(m, d, 64);
            const float os = __shfl_xor(s, d, 64);
            const float nm = fmaxf(m, om);
            s = __expf(m - nm) * s + __expf(om - nm) * os;
            m = nm;
        }
        const float vsink = m + __logf(s);
        #pragma unroll
        for (int d = 1; d < 64; d <<= 1) gs += __shfl_xor(gs, d, 64);
        if (l == 0) out[0] = gs + vsink;
    }
}

extern "C" void kernel_launch(void* const* d_in, const int* in_sizes, int n_in,
                              void* d_out, int out_size, void* d_ws, size_t ws_size,
                              hipStream_t stream) {
    const int*   g = (const int*)d_in[0];
    const float* w = (const float*)d_in[1];
    float* out     = (float*)d_out;
    unsigned int* wpk = (unsigned int*)d_ws;        // 129024 u32
    float* partial = (float*)(wpk + NPACK);         // 256 floats
    const int E = in_sizes[0] / 3;                  // 258176

    prep_kernel<<<NPB, 512, 0, stream>>>(g, w, wpk, partial, E);
    seq_kernel<<<1, 256, 0, stream>>>(w, wpk, partial, out);
}